// Round 1
// baseline (38.475 us; speedup 1.0000x reference)
//
#include <hip/hip_runtime.h>

// AttnCutLoss: loss = -mean_b sum_j log(output[b,j]) * softmax_j(f1(labels[b,:j+1]) / tau)
// f1 at cutoff k with csum c, total t:  2*(c/k)*(c/t) / (c/k + c/t) = 2c/(k+t)   (0 if t==0)

constexpr int L   = 2048;
constexpr int TPB = 256;
constexpr int EPT = L / TPB;          // 8 elements per thread
constexpr float TAU = 0.95f;

__global__ __launch_bounds__(TPB) void attncut_row_kernel(
    const float* __restrict__ output,   // [B, L] (inner dim 1 squeezed)
    const float* __restrict__ labels,   // [B, L]
    float* __restrict__ rowloss,        // [B]
    int B)
{
    const int row  = blockIdx.x;
    const int t    = threadIdx.x;
    const int lane = t & 63;
    const int wave = t >> 6;

    // ---- load labels: 8 contiguous floats per thread (coalesced float4 x2) ----
    const float* lab = labels + (size_t)row * L + (size_t)t * EPT;
    float4 a0 = reinterpret_cast<const float4*>(lab)[0];
    float4 a1 = reinterpret_cast<const float4*>(lab)[1];
    float v[EPT] = {a0.x, a0.y, a0.z, a0.w, a1.x, a1.y, a1.z, a1.w};

    // per-thread inclusive prefix
    float p[EPT];
    float run = 0.f;
#pragma unroll
    for (int i = 0; i < EPT; ++i) { run += v[i]; p[i] = run; }

    // ---- wave-level inclusive scan of per-thread sums ----
    float x = run;
#pragma unroll
    for (int d = 1; d < 64; d <<= 1) {
        float n = __shfl_up(x, d, 64);
        if (lane >= d) x += n;
    }

    __shared__ float wsum[4];
    if (lane == 63) wsum[wave] = x;
    __syncthreads();
    const float w0 = wsum[0], w1 = wsum[1], w2 = wsum[2], w3 = wsum[3];
    const float total = w0 + w1 + w2 + w3;
    float waveoff = 0.f;
    if (wave > 0) waveoff += w0;
    if (wave > 1) waveoff += w1;
    if (wave > 2) waveoff += w2;
    const float excl = waveoff + (x - run);   // exclusive prefix for this thread's chunk

    // ---- f1 -> s = r/tau, track max ----
    const bool tpos = total > 0.f;
    float s[EPT];
    float m = -1e30f;
#pragma unroll
    for (int i = 0; i < EPT; ++i) {
        float c = excl + p[i];
        float k = (float)(t * EPT + i + 1);
        float r = tpos ? (2.f * c / (k + total)) : 0.f;
        s[i] = r * (1.0f / TAU);
        m = fmaxf(m, s[i]);
    }
    // block max reduce
#pragma unroll
    for (int d = 32; d; d >>= 1) m = fmaxf(m, __shfl_xor(m, d, 64));
    __shared__ float wmax[4];
    if (lane == 0) wmax[wave] = m;
    __syncthreads();
    m = fmaxf(fmaxf(wmax[0], wmax[1]), fmaxf(wmax[2], wmax[3]));

    // ---- exp + dot with log(output) ----
    const float* op = output + (size_t)row * L + (size_t)t * EPT;
    float4 o0 = reinterpret_cast<const float4*>(op)[0];
    float4 o1 = reinterpret_cast<const float4*>(op)[1];
    float ov[EPT] = {o0.x, o0.y, o0.z, o0.w, o1.x, o1.y, o1.z, o1.w};

    float Z = 0.f, W = 0.f;
#pragma unroll
    for (int i = 0; i < EPT; ++i) {
        float e = expf(s[i] - m);
        Z += e;
        W += logf(ov[i]) * e;
    }
#pragma unroll
    for (int d = 32; d; d >>= 1) {
        Z += __shfl_xor(Z, d, 64);
        W += __shfl_xor(W, d, 64);
    }
    __shared__ float wZ[4], wW[4];
    if (lane == 0) { wZ[wave] = Z; wW[wave] = W; }
    __syncthreads();
    if (t == 0) {
        float Zt = wZ[0] + wZ[1] + wZ[2] + wZ[3];
        float Wt = wW[0] + wW[1] + wW[2] + wW[3];
        rowloss[row] = -Wt / Zt;
    }
}

__global__ __launch_bounds__(TPB) void attncut_reduce_kernel(
    const float* __restrict__ rowloss, float* __restrict__ out, int B)
{
    const int t = threadIdx.x;
    float s = 0.f;
    for (int i = t; i < B; i += TPB) s += rowloss[i];
#pragma unroll
    for (int d = 32; d; d >>= 1) s += __shfl_xor(s, d, 64);
    __shared__ float ws[4];
    if ((t & 63) == 0) ws[t >> 6] = s;
    __syncthreads();
    if (t == 0) out[0] = (ws[0] + ws[1] + ws[2] + ws[3]) / (float)B;
}

extern "C" void kernel_launch(void* const* d_in, const int* in_sizes, int n_in,
                              void* d_out, int out_size, void* d_ws, size_t ws_size,
                              hipStream_t stream) {
    const float* output = (const float*)d_in[0];   // [B, L, 1] fp32
    const float* labels = (const float*)d_in[1];   // [B, L]    fp32
    const int B = in_sizes[1] / L;                 // 8192

    float* rowloss = (float*)d_ws;                 // B floats = 32 KB scratch

    attncut_row_kernel<<<B, TPB, 0, stream>>>(output, labels, rowloss, B);
    attncut_reduce_kernel<<<1, TPB, 0, stream>>>(rowloss, (float*)d_out, B);
}

// Round 2
// 34.832 us; speedup vs baseline: 1.1046x; 1.1046x over previous
//
#include <hip/hip_runtime.h>

// AttnCutLoss: loss = -mean_b sum_j log(output[b,j]) * softmax_j(f1(labels[b,:j+1]) / tau)
// f1 at cutoff k with csum c, total t:  2*(c/k)*(c/t) / (c/k + c/t) = 2c/(k+t)   (0 if t==0)
//
// Base-2 formulation: softmax_j(r/tau) = exp2(s_j - m) / sum exp2(s_j - m),
//   s_j = r_j * log2(e)/tau = (2*log2e/tau) * c_j * rcp(k_j + total)
// ln(o) = ln2 * log2(o).  All transcendentals map to single v_rcp/v_exp/v_log.

constexpr int L   = 2048;
constexpr int TPB = 256;
constexpr int EPT = L / TPB;          // 8 elements per thread
constexpr float TAU    = 0.95f;
constexpr float LOG2E  = 1.4426950408889634f;
constexpr float LN2    = 0.6931471805599453f;

__global__ __launch_bounds__(TPB) void attncut_row_kernel(
    const float* __restrict__ output,   // [B, L] (inner dim 1 squeezed)
    const float* __restrict__ labels,   // [B, L]
    float* __restrict__ rowloss,        // [B]
    int B)
{
    const int row  = blockIdx.x;
    const int t    = threadIdx.x;
    const int lane = t & 63;
    const int wave = t >> 6;

    // ---- issue BOTH row loads up front (coalesced float4) ----
    const float* lab = labels + (size_t)row * L + (size_t)t * EPT;
    const float* op  = output + (size_t)row * L + (size_t)t * EPT;
    float4 a0 = reinterpret_cast<const float4*>(lab)[0];
    float4 a1 = reinterpret_cast<const float4*>(lab)[1];
    float4 o0 = reinterpret_cast<const float4*>(op)[0];
    float4 o1 = reinterpret_cast<const float4*>(op)[1];
    float v[EPT]  = {a0.x, a0.y, a0.z, a0.w, a1.x, a1.y, a1.z, a1.w};
    float ov[EPT] = {o0.x, o0.y, o0.z, o0.w, o1.x, o1.y, o1.z, o1.w};

    // per-thread inclusive prefix
    float p[EPT];
    float run = 0.f;
#pragma unroll
    for (int i = 0; i < EPT; ++i) { run += v[i]; p[i] = run; }

    // ---- wave-level inclusive scan of per-thread sums ----
    float x = run;
#pragma unroll
    for (int d = 1; d < 64; d <<= 1) {
        float n = __shfl_up(x, d, 64);
        if (lane >= d) x += n;
    }

    __shared__ float wsum[4];
    if (lane == 63) wsum[wave] = x;
    __syncthreads();
    const float w0 = wsum[0], w1 = wsum[1], w2 = wsum[2], w3 = wsum[3];
    const float total = w0 + w1 + w2 + w3;
    float waveoff = 0.f;
    if (wave > 0) waveoff += w0;
    if (wave > 1) waveoff += w1;
    if (wave > 2) waveoff += w2;
    const float excl = waveoff + (x - run);   // exclusive prefix for this thread's chunk

    // ---- s = r * log2e/tau via hardware rcp; also log2(output); track max ----
    const float K2 = (total > 0.f) ? (2.f * LOG2E / TAU) : 0.f;
    const float kbase = (float)(t * EPT) + total;
    float s[EPT], lg[EPT];
    float m = -1e30f;
#pragma unroll
    for (int i = 0; i < EPT; ++i) {
        float c  = excl + p[i];
        float kd = kbase + (float)(i + 1);
        s[i] = (K2 * c) * __builtin_amdgcn_rcpf(kd);
        lg[i] = __builtin_amdgcn_logf(ov[i]);     // log2(o)
        m = fmaxf(m, s[i]);
    }
    // block max reduce
#pragma unroll
    for (int d = 32; d; d >>= 1) m = fmaxf(m, __shfl_xor(m, d, 64));
    __shared__ float wmax[4];
    if (lane == 0) wmax[wave] = m;
    __syncthreads();
    m = fmaxf(fmaxf(wmax[0], wmax[1]), fmaxf(wmax[2], wmax[3]));

    // ---- exp2 + dot ----
    float Z = 0.f, W = 0.f;
#pragma unroll
    for (int i = 0; i < EPT; ++i) {
        float e = __builtin_amdgcn_exp2f(s[i] - m);
        Z += e;
        W = fmaf(lg[i], e, W);
    }
#pragma unroll
    for (int d = 32; d; d >>= 1) {
        Z += __shfl_xor(Z, d, 64);
        W += __shfl_xor(W, d, 64);
    }
    __shared__ float wZ[4], wW[4];
    if (lane == 0) { wZ[wave] = Z; wW[wave] = W; }
    __syncthreads();
    if (t == 0) {
        float Zt = wZ[0] + wZ[1] + wZ[2] + wZ[3];
        float Wt = wW[0] + wW[1] + wW[2] + wW[3];
        rowloss[row] = -LN2 * Wt / Zt;
    }
}

__global__ __launch_bounds__(TPB) void attncut_reduce_kernel(
    const float* __restrict__ rowloss, float* __restrict__ out, int B)
{
    const int t = threadIdx.x;
    float s = 0.f;
    for (int i = t; i < B; i += TPB) s += rowloss[i];
#pragma unroll
    for (int d = 32; d; d >>= 1) s += __shfl_xor(s, d, 64);
    __shared__ float ws[4];
    if ((t & 63) == 0) ws[t >> 6] = s;
    __syncthreads();
    if (t == 0) out[0] = (ws[0] + ws[1] + ws[2] + ws[3]) / (float)B;
}

extern "C" void kernel_launch(void* const* d_in, const int* in_sizes, int n_in,
                              void* d_out, int out_size, void* d_ws, size_t ws_size,
                              hipStream_t stream) {
    const float* output = (const float*)d_in[0];   // [B, L, 1] fp32
    const float* labels = (const float*)d_in[1];   // [B, L]    fp32
    const int B = in_sizes[1] / L;                 // 8192

    float* rowloss = (float*)d_ws;                 // B floats = 32 KB scratch

    attncut_row_kernel<<<B, TPB, 0, stream>>>(output, labels, rowloss, B);
    attncut_reduce_kernel<<<1, TPB, 0, stream>>>(rowloss, (float*)d_out, B);
}

// Round 3
// 31.761 us; speedup vs baseline: 1.2114x; 1.0967x over previous
//
#include <hip/hip_runtime.h>

// AttnCutLoss: loss = -mean_b sum_j log(output[b,j]) * softmax_j(f1(labels[b,:j+1]) / tau)
// f1 at cutoff k (csum c, total t): 2c/(k+t), 0 if t==0.
//
// s_j = (2*log2e/tau) * c_j / (k_j + t)  in [0, log2e/tau ~ 1.52]  -> exp2 needs NO
// max-subtract (softmax shift-invariant, exp2(s) in [1, 2.87]).  ln(o) = ln2*log2(o).
//
// One wave per row: lane l owns elements [32l, 32l+32). Labels (exactly 0/1) pack
// into a 32-bit mask per lane; cumsum = wave-scan of popcounts + bit walk.
// No __syncthreads, no LDS in the row kernel.

constexpr int L   = 2048;
constexpr int TPB = 256;                 // 4 waves = 4 rows per block
constexpr int EPL = 32;                  // elements per lane
constexpr float TAU   = 0.95f;
constexpr float LOG2E = 1.4426950408889634f;
constexpr float LN2   = 0.6931471805599453f;

__global__ __launch_bounds__(TPB) void attncut_row_kernel(
    const float* __restrict__ output,   // [B, L]
    const float* __restrict__ labels,   // [B, L]
    float* __restrict__ rowloss,        // [B]
    int B)
{
    const int wave = threadIdx.x >> 6;
    const int lane = threadIdx.x & 63;
    const int row  = blockIdx.x * 4 + wave;

    const size_t base = (size_t)row * L + (size_t)lane * EPL;
    const float4* lab4 = reinterpret_cast<const float4*>(labels + base);
    const float4* out4 = reinterpret_cast<const float4*>(output + base);

    // ---- labels -> 32-bit mask (labels are exactly 0.0/1.0) ----
    unsigned mask = 0u;
#pragma unroll
    for (int c = 0; c < 8; ++c) {
        float4 a = lab4[c];
        unsigned b0 = (unsigned)a.x, b1 = (unsigned)a.y,
                 b2 = (unsigned)a.z, b3 = (unsigned)a.w;
        mask |= (b0 << (4*c)) | (b1 << (4*c+1)) | (b2 << (4*c+2)) | (b3 << (4*c+3));
    }

    // ---- issue output row loads early (consumed in main loop) ----
    float4 o[8];
#pragma unroll
    for (int c = 0; c < 8; ++c) o[c] = out4[c];

    // ---- wave inclusive scan of per-lane label counts ----
    const float run = (float)__popc(mask);
    float x = run;
#pragma unroll
    for (int d = 1; d < 64; d <<= 1) {
        float n = __shfl_up(x, d, 64);
        if (lane >= d) x += n;
    }
    const float total = __shfl(x, 63, 64);
    const float excl  = x - run;

    const float K2 = (total > 0.f) ? (2.f * LOG2E / TAU) : 0.f;
    const float kbase = (float)(lane * EPL) + total;

    // ---- main loop: no max needed (s bounded by ~1.52) ----
    float cf = excl;
    float Z = 0.f, W = 0.f;
    const float* of = reinterpret_cast<const float*>(o);
#pragma unroll
    for (int i = 0; i < EPL; ++i) {
        cf += (float)((mask >> i) & 1u);
        float s = (K2 * cf) * __builtin_amdgcn_rcpf(kbase + (float)(i + 1));
        float e = __builtin_amdgcn_exp2f(s);
        Z += e;
        W = fmaf(__builtin_amdgcn_logf(of[i]), e, W);   // log2(o)
    }

    // ---- wave reduce Z, W ----
#pragma unroll
    for (int d = 32; d; d >>= 1) {
        Z += __shfl_xor(Z, d, 64);
        W += __shfl_xor(W, d, 64);
    }
    if (lane == 0) rowloss[row] = -LN2 * W / Z;
}

__global__ __launch_bounds__(TPB) void attncut_reduce_kernel(
    const float* __restrict__ rowloss, float* __restrict__ out, int B)
{
    const int t = threadIdx.x;
    const float4* r4 = reinterpret_cast<const float4*>(rowloss);
    float s = 0.f;
    for (int i = t; i < B / 4; i += TPB) {
        float4 v = r4[i];
        s += (v.x + v.y) + (v.z + v.w);
    }
#pragma unroll
    for (int d = 32; d; d >>= 1) s += __shfl_xor(s, d, 64);
    __shared__ float ws[4];
    if ((t & 63) == 0) ws[t >> 6] = s;
    __syncthreads();
    if (t == 0) out[0] = (ws[0] + ws[1] + ws[2] + ws[3]) / (float)B;
}

extern "C" void kernel_launch(void* const* d_in, const int* in_sizes, int n_in,
                              void* d_out, int out_size, void* d_ws, size_t ws_size,
                              hipStream_t stream) {
    const float* output = (const float*)d_in[0];   // [B, L, 1] fp32
    const float* labels = (const float*)d_in[1];   // [B, L]    fp32
    const int B = in_sizes[1] / L;                 // 8192

    float* rowloss = (float*)d_ws;                 // B floats = 32 KB scratch

    attncut_row_kernel<<<B / 4, TPB, 0, stream>>>(output, labels, rowloss, B);
    attncut_reduce_kernel<<<1, TPB, 0, stream>>>(rowloss, (float*)d_out, B);
}

// Round 4
// 28.688 us; speedup vs baseline: 1.3412x; 1.1071x over previous
//
#include <hip/hip_runtime.h>

// AttnCutLoss: loss = -mean_b sum_j log(output[b,j]) * softmax_j(f1(labels[b,:j+1]) / tau)
// f1 at cutoff k (csum c, total t): 2c/(k+t), 0 if t==0.
//
// s_j = (2*log2e/tau) * c_j / (k_j + t) in [0, ~1.52] -> exp2 needs no max-subtract.
// ln(o) = ln2 * log2(o). One wave per row, no LDS, no __syncthreads.
//
// COALESCED ownership: lane i owns float4 [c*256 + 4i, +4) for chunks c=0..7.
// Every global load is a contiguous 1KB wave transaction (8 cache lines, not 64).
// Cumsum: per-chunk per-lane counts (0..4) packed 2-per-word (16-bit fields) into
// 4 words; 4 packed wave-scans give all 8 chunk lane-prefixes + chunk totals.

constexpr int L   = 2048;
constexpr int TPB = 256;                 // 4 waves = 4 rows per block
constexpr float TAU   = 0.95f;
constexpr float LOG2E = 1.4426950408889634f;
constexpr float LN2   = 0.6931471805599453f;

__global__ __launch_bounds__(TPB) void attncut_row_kernel(
    const float* __restrict__ output,   // [B, L]
    const float* __restrict__ labels,   // [B, L]
    float* __restrict__ rowloss,        // [B]
    int B)
{
    const int wave = threadIdx.x >> 6;
    const int lane = threadIdx.x & 63;
    const int row  = blockIdx.x * 4 + wave;

    const float4* lab4 = reinterpret_cast<const float4*>(labels + (size_t)row * L) + lane;
    const float4* out4 = reinterpret_cast<const float4*>(output + (size_t)row * L) + lane;

    // ---- labels -> 4-bit nibble per chunk, packed into one 32-bit reg ----
    unsigned nibs = 0u;
#pragma unroll
    for (int c = 0; c < 8; ++c) {
        float4 a = lab4[c * 64];                      // coalesced: lanes contiguous
        unsigned b = (unsigned)a.x | ((unsigned)a.y << 1)
                   | ((unsigned)a.z << 2) | ((unsigned)a.w << 3);
        nibs |= b << (4 * c);
    }

    // ---- pack per-chunk counts (0..4) into 4 words, 16-bit fields (2 chunks/word) ----
    unsigned w[4];
#pragma unroll
    for (int q = 0; q < 4; ++q) {
        unsigned c0 = __popc((nibs >> (8 * q)) & 0xFu);
        unsigned c1 = __popc((nibs >> (8 * q + 4)) & 0xFu);
        w[q] = c0 | (c1 << 16);
    }

    // ---- 4 packed inclusive wave-scans (independent chains, pipeline) ----
#pragma unroll
    for (int d = 1; d < 64; d <<= 1) {
#pragma unroll
        for (int q = 0; q < 4; ++q) {
            unsigned n = __shfl_up(w[q], d, 64);
            if (lane >= d) w[q] += n;
        }
    }

    // ---- chunk totals (lane 63) and per-lane exclusive prefixes ----
    float T[8], E[8];
#pragma unroll
    for (int q = 0; q < 4; ++q) {
        unsigned tw = __shfl(w[q], 63, 64);
        unsigned own0 = __popc((nibs >> (8 * q)) & 0xFu);
        unsigned own1 = __popc((nibs >> (8 * q + 4)) & 0xFu);
        T[2 * q]     = (float)(tw & 0xFFFFu);
        T[2 * q + 1] = (float)(tw >> 16);
        E[2 * q]     = (float)((w[q] & 0xFFFFu) - own0);
        E[2 * q + 1] = (float)((w[q] >> 16) - own1);
    }
    const float total = ((T[0] + T[1]) + (T[2] + T[3])) + ((T[4] + T[5]) + (T[6] + T[7]));

    const float K2 = (total > 0.f) ? (2.f * LOG2E / TAU) : 0.f;

    // ---- main loop over chunks: coalesced output loads, exp2/log2/rcp ----
    float Z = 0.f, Wd = 0.f;
    float off = 0.f;
#pragma unroll
    for (int c = 0; c < 8; ++c) {
        float4 ov = out4[c * 64];
        float cf = off + E[c];
        const unsigned nib = (nibs >> (4 * c)) & 0xFu;
        const float kb = total + (float)(c * 256 + 4 * lane);

        cf += (float)(nib & 1u);
        float e0 = __builtin_amdgcn_exp2f((K2 * cf) * __builtin_amdgcn_rcpf(kb + 1.f));
        Z += e0;  Wd = fmaf(__builtin_amdgcn_logf(ov.x), e0, Wd);

        cf += (float)((nib >> 1) & 1u);
        float e1 = __builtin_amdgcn_exp2f((K2 * cf) * __builtin_amdgcn_rcpf(kb + 2.f));
        Z += e1;  Wd = fmaf(__builtin_amdgcn_logf(ov.y), e1, Wd);

        cf += (float)((nib >> 2) & 1u);
        float e2 = __builtin_amdgcn_exp2f((K2 * cf) * __builtin_amdgcn_rcpf(kb + 3.f));
        Z += e2;  Wd = fmaf(__builtin_amdgcn_logf(ov.z), e2, Wd);

        cf += (float)((nib >> 3) & 1u);
        float e3 = __builtin_amdgcn_exp2f((K2 * cf) * __builtin_amdgcn_rcpf(kb + 4.f));
        Z += e3;  Wd = fmaf(__builtin_amdgcn_logf(ov.w), e3, Wd);

        off += T[c];
    }

    // ---- wave reduce Z, Wd ----
#pragma unroll
    for (int d = 32; d; d >>= 1) {
        Z  += __shfl_xor(Z, d, 64);
        Wd += __shfl_xor(Wd, d, 64);
    }
    if (lane == 0) rowloss[row] = -LN2 * Wd / Z;
}

__global__ __launch_bounds__(TPB) void attncut_reduce_kernel(
    const float* __restrict__ rowloss, float* __restrict__ out, int B)
{
    const int t = threadIdx.x;
    const float4* r4 = reinterpret_cast<const float4*>(rowloss);
    float s = 0.f;
    for (int i = t; i < B / 4; i += TPB) {
        float4 v = r4[i];
        s += (v.x + v.y) + (v.z + v.w);
    }
#pragma unroll
    for (int d = 32; d; d >>= 1) s += __shfl_xor(s, d, 64);
    __shared__ float ws[4];
    if ((t & 63) == 0) ws[t >> 6] = s;
    __syncthreads();
    if (t == 0) out[0] = (ws[0] + ws[1] + ws[2] + ws[3]) / (float)B;
}

extern "C" void kernel_launch(void* const* d_in, const int* in_sizes, int n_in,
                              void* d_out, int out_size, void* d_ws, size_t ws_size,
                              hipStream_t stream) {
    const float* output = (const float*)d_in[0];   // [B, L, 1] fp32
    const float* labels = (const float*)d_in[1];   // [B, L]    fp32
    const int B = in_sizes[1] / L;                 // 8192

    float* rowloss = (float*)d_ws;                 // B floats = 32 KB scratch

    attncut_row_kernel<<<B / 4, TPB, 0, stream>>>(output, labels, rowloss, B);
    attncut_reduce_kernel<<<1, TPB, 0, stream>>>(rowloss, (float*)d_out, B);
}

// Round 5
// 28.184 us; speedup vs baseline: 1.3652x; 1.0179x over previous
//
#include <hip/hip_runtime.h>

// AttnCutLoss: loss = -mean_b sum_j log(output[b,j]) * softmax_j(f1(labels[b,:j+1]) / tau)
// f1 at cutoff k (csum c, total t): 2c/(k+t), 0 if t==0.
//
// s_j = (2*log2e/tau) * c_j / (k_j + t) in [0, ~1.52] -> exp2 needs no max-subtract.
// ln(o) = ln2 * log2(o). One wave per row, no LDS, no __syncthreads.
//
// COALESCED ownership: lane i owns float4 [c*256 + 4i, +4) for chunks c=0..7.
// ALL 16 loads (8 label + 8 output float4) issued up front -> 16-deep MLP per wave;
// label->bitmask conversion and the packed wave-scan overlap the output loads' latency.

constexpr int L   = 2048;
constexpr int TPB = 256;                 // 4 waves = 4 rows per block
constexpr float TAU   = 0.95f;
constexpr float LOG2E = 1.4426950408889634f;
constexpr float LN2   = 0.6931471805599453f;

__global__ __launch_bounds__(TPB) void attncut_row_kernel(
    const float* __restrict__ output,   // [B, L]
    const float* __restrict__ labels,   // [B, L]
    float* __restrict__ rowloss,        // [B]
    int B)
{
    const int wave = threadIdx.x >> 6;
    const int lane = threadIdx.x & 63;
    const int row  = blockIdx.x * 4 + wave;

    const float4* lab4 = reinterpret_cast<const float4*>(labels + (size_t)row * L) + lane;
    const float4* out4 = reinterpret_cast<const float4*>(output + (size_t)row * L) + lane;

    // ---- issue ALL loads up front: 16 outstanding 1KB wave-transactions ----
    float4 lb[8], ov[8];
#pragma unroll
    for (int c = 0; c < 8; ++c) lb[c] = lab4[c * 64];
#pragma unroll
    for (int c = 0; c < 8; ++c) ov[c] = out4[c * 64];

    // ---- labels -> 4-bit nibble per chunk (waits only on label loads) ----
    unsigned nibs = 0u;
#pragma unroll
    for (int c = 0; c < 8; ++c) {
        float4 a = lb[c];
        unsigned b = (unsigned)a.x | ((unsigned)a.y << 1)
                   | ((unsigned)a.z << 2) | ((unsigned)a.w << 3);
        nibs |= b << (4 * c);
    }

    // ---- pack per-chunk counts (0..4) into 4 words, 16-bit fields (2 chunks/word) ----
    unsigned w[4];
#pragma unroll
    for (int q = 0; q < 4; ++q) {
        unsigned c0 = __popc((nibs >> (8 * q)) & 0xFu);
        unsigned c1 = __popc((nibs >> (8 * q + 4)) & 0xFu);
        w[q] = c0 | (c1 << 16);
    }

    // ---- 4 packed inclusive wave-scans (independent chains, overlap output loads) ----
#pragma unroll
    for (int d = 1; d < 64; d <<= 1) {
#pragma unroll
        for (int q = 0; q < 4; ++q) {
            unsigned n = __shfl_up(w[q], d, 64);
            if (lane >= d) w[q] += n;
        }
    }

    // ---- chunk totals (lane 63) and per-lane exclusive prefixes ----
    float T[8], E[8];
#pragma unroll
    for (int q = 0; q < 4; ++q) {
        unsigned tw = __shfl(w[q], 63, 64);
        unsigned own0 = __popc((nibs >> (8 * q)) & 0xFu);
        unsigned own1 = __popc((nibs >> (8 * q + 4)) & 0xFu);
        T[2 * q]     = (float)(tw & 0xFFFFu);
        T[2 * q + 1] = (float)(tw >> 16);
        E[2 * q]     = (float)((w[q] & 0xFFFFu) - own0);
        E[2 * q + 1] = (float)((w[q] >> 16) - own1);
    }
    const float total = ((T[0] + T[1]) + (T[2] + T[3])) + ((T[4] + T[5]) + (T[6] + T[7]));

    const float K2 = (total > 0.f) ? (2.f * LOG2E / TAU) : 0.f;

    // ---- main loop over chunks: outputs already in flight/registers ----
    float Z = 0.f, Wd = 0.f;
    float off = 0.f;
#pragma unroll
    for (int c = 0; c < 8; ++c) {
        float4 o = ov[c];
        float cf = off + E[c];
        const unsigned nib = (nibs >> (4 * c)) & 0xFu;
        const float kb = total + (float)(c * 256 + 4 * lane);

        cf += (float)(nib & 1u);
        float e0 = __builtin_amdgcn_exp2f((K2 * cf) * __builtin_amdgcn_rcpf(kb + 1.f));
        Z += e0;  Wd = fmaf(__builtin_amdgcn_logf(o.x), e0, Wd);

        cf += (float)((nib >> 1) & 1u);
        float e1 = __builtin_amdgcn_exp2f((K2 * cf) * __builtin_amdgcn_rcpf(kb + 2.f));
        Z += e1;  Wd = fmaf(__builtin_amdgcn_logf(o.y), e1, Wd);

        cf += (float)((nib >> 2) & 1u);
        float e2 = __builtin_amdgcn_exp2f((K2 * cf) * __builtin_amdgcn_rcpf(kb + 3.f));
        Z += e2;  Wd = fmaf(__builtin_amdgcn_logf(o.z), e2, Wd);

        cf += (float)((nib >> 3) & 1u);
        float e3 = __builtin_amdgcn_exp2f((K2 * cf) * __builtin_amdgcn_rcpf(kb + 4.f));
        Z += e3;  Wd = fmaf(__builtin_amdgcn_logf(o.w), e3, Wd);

        off += T[c];
    }

    // ---- wave reduce Z, Wd ----
#pragma unroll
    for (int d = 32; d; d >>= 1) {
        Z  += __shfl_xor(Z, d, 64);
        Wd += __shfl_xor(Wd, d, 64);
    }
    if (lane == 0) rowloss[row] = -LN2 * Wd / Z;
}

__global__ __launch_bounds__(1024) void attncut_reduce_kernel(
    const float* __restrict__ rowloss, float* __restrict__ out, int B)
{
    const int t = threadIdx.x;
    const float4* r4 = reinterpret_cast<const float4*>(rowloss);
    float s = 0.f;
    for (int i = t; i < B / 4; i += 1024) {
        float4 v = r4[i];
        s += (v.x + v.y) + (v.z + v.w);
    }
#pragma unroll
    for (int d = 32; d; d >>= 1) s += __shfl_xor(s, d, 64);
    __shared__ float ws[16];
    if ((t & 63) == 0) ws[t >> 6] = s;
    __syncthreads();
    if (t < 16) {
        s = ws[t];
#pragma unroll
        for (int d = 8; d; d >>= 1) s += __shfl_xor(s, d, 64);
        if (t == 0) out[0] = s / (float)B;
    }
}

extern "C" void kernel_launch(void* const* d_in, const int* in_sizes, int n_in,
                              void* d_out, int out_size, void* d_ws, size_t ws_size,
                              hipStream_t stream) {
    const float* output = (const float*)d_in[0];   // [B, L, 1] fp32
    const float* labels = (const float*)d_in[1];   // [B, L]    fp32
    const int B = in_sizes[1] / L;                 // 8192

    float* rowloss = (float*)d_ws;                 // B floats = 32 KB scratch

    attncut_row_kernel<<<B / 4, TPB, 0, stream>>>(output, labels, rowloss, B);
    attncut_reduce_kernel<<<1, 1024, 0, stream>>>(rowloss, (float*)d_out, B);
}